// Round 1
// baseline (416.400 us; speedup 1.0000x reference)
//
#include <hip/hip_runtime.h>
#include <math.h>

#define P 45
#define N_ITER 20

__global__ __launch_bounds__(64) void drb_kernel(
    const float* __restrict__ sigma,
    const float* __restrict__ beta,
    const float* __restrict__ w_prev,
    const float* __restrict__ lls,
    const float* __restrict__ llt,
    float* __restrict__ out)
{
    const int b    = blockIdx.x;
    const int lane = threadIdx.x;

    // scalars (1-element arrays); uniform across all lanes
    const float lam_s  = expf(lls[0]);
    const float lam_t2 = 2.0f * expf(llt[0]);

    const size_t base = (size_t)b * (P * P);

    // Lane i (i < P) owns row i of sigma in registers.
    float row[P];
    float bet = 0.0f, wp = 0.0f, wc = 0.0f;
    if (lane < P) {
        const float* rp = sigma + base + (size_t)lane * P;
        #pragma unroll
        for (int j = 0; j < P; ++j) row[j] = rp[j];
        bet = beta[(size_t)b * P + lane];
        wp  = w_prev[(size_t)b * P + lane];
        wc  = (float)(1.0 / 45.0);   // match numpy's f64->f32 constant
    } else {
        #pragma unroll
        for (int j = 0; j < P; ++j) row[j] = 0.0f;
        // bet = wp = wc = 0 -> lanes >= P carry exact zeros through all iters
    }

    __shared__ __align__(16) float w_sh[P];
    if (lane < P) w_sh[lane] = wc;
    __syncthreads();

    for (int it = 0; it < N_ITER; ++it) {
        // Broadcast-read full w vector from LDS (uniform addresses, no conflicts)
        float wv[P];
        #pragma unroll
        for (int j = 0; j < P; ++j) wv[j] = w_sh[j];

        // Sw_i = row_i . w
        float acc = 0.0f;
        #pragma unroll
        for (int j = 0; j < P; ++j) acc = fmaf(row[j], wv[j], acc);

        // gradient step
        float sgn = (wc > 0.0f) ? 1.0f : ((wc < 0.0f) ? -1.0f : 0.0f);
        float g   = 2.0f * acc - bet + lam_s * sgn + lam_t2 * (wc - wp);
        float wn  = wc - 0.05f * g;

        // simplex projection: clip, renorm, clip, renorm
        wn = fminf(fmaxf(wn, 0.0f), 0.15f);
        float s = wn;
        #pragma unroll
        for (int m = 1; m < 64; m <<= 1) s += __shfl_xor(s, m, 64);
        wn = wn / (s + 1e-8f);

        wn = fminf(fmaxf(wn, 0.0f), 0.15f);
        float s2 = wn;
        #pragma unroll
        for (int m = 1; m < 64; m <<= 1) s2 += __shfl_xor(s2, m, 64);
        wn = wn / (s2 + 1e-8f);

        wc = wn;

        __syncthreads();               // all reads of w_sh for this iter done
        if (lane < P) w_sh[lane] = wc; // publish new w
        __syncthreads();               // visible before next iter's reads
    }

    if (lane < P) out[(size_t)b * P + lane] = wc;
}

extern "C" void kernel_launch(void* const* d_in, const int* in_sizes, int n_in,
                              void* d_out, int out_size, void* d_ws, size_t ws_size,
                              hipStream_t stream) {
    const float* sigma  = (const float*)d_in[0];
    const float* beta   = (const float*)d_in[1];
    const float* w_prev = (const float*)d_in[2];
    const float* lls    = (const float*)d_in[3];
    const float* llt    = (const float*)d_in[4];
    float* out = (float*)d_out;

    const int B = in_sizes[1] / P;   // 32768
    drb_kernel<<<B, 64, 0, stream>>>(sigma, beta, w_prev, lls, llt, out);
}

// Round 2
// 394.441 us; speedup vs baseline: 1.0557x; 1.0557x over previous
//
#include <hip/hip_runtime.h>
#include <math.h>

#define P 45
#define N_ITER 20

// Pure-VALU cross-lane add via DPP (no LDS pipe, unlike __shfl_xor/ds_swizzle).
template<int CTRL>
__device__ __forceinline__ float dpp_add(float x) {
    int xi = __builtin_bit_cast(int, x);
    int yi = __builtin_amdgcn_update_dpp(0, xi, CTRL, 0xF, 0xF, true);
    return x + __builtin_bit_cast(float, yi);
}

// Full wave64 sum, result broadcast to all lanes (via readlane -> SGPR).
__device__ __forceinline__ float wave_sum_bcast(float x) {
    x = dpp_add<0x111>(x); // row_shr:1
    x = dpp_add<0x112>(x); // row_shr:2
    x = dpp_add<0x114>(x); // row_shr:4
    x = dpp_add<0x118>(x); // row_shr:8  -> lane 15/31/47/63 hold row sums
    x = dpp_add<0x142>(x); // row_bcast:15 -> lane 31 = sum(0..31), lane 63 = sum(32..63)
    x = dpp_add<0x143>(x); // row_bcast:31 -> lane 63 = sum(0..63)
    int si = __builtin_amdgcn_readlane(__builtin_bit_cast(int, x), 63);
    return __builtin_bit_cast(float, si);
}

__global__ __launch_bounds__(64) void drb_kernel(
    const float* __restrict__ sigma,
    const float* __restrict__ beta,
    const float* __restrict__ w_prev,
    const float* __restrict__ lls,
    const float* __restrict__ llt,
    float* __restrict__ out)
{
    const int b    = blockIdx.x;
    const int lane = threadIdx.x;
    const bool active = lane < P;
    const int  r   = active ? lane : (P - 1);   // clamp: lanes >=P load a dup row (harmless)

    const float lam_s  = expf(lls[0]);
    const float lam_t2 = 2.0f * expf(llt[0]);

    // Lane i owns row i of sigma, pinned in VGPRs.
    const float* rp = sigma + (size_t)b * (P * P) + (size_t)r * P;
    float row[P];
    #pragma unroll
    for (int j = 0; j < P; ++j) row[j] = rp[j];
    // Block rematerialization: force each element to live in a VGPR.
    #pragma unroll
    for (int j = 0; j < P; ++j) asm volatile("" : "+v"(row[j]));

    float bet = active ? beta[(size_t)b * P + lane]   : 0.0f;
    float wp  = active ? w_prev[(size_t)b * P + lane] : 0.0f;
    float wc  = active ? (float)(1.0 / 45.0)          : 0.0f;

    for (int it = 0; it < N_ITER; ++it) {
        // Sw_i = row_i . w ; w_j fetched from lane j via readlane (SGPR operand FMAs).
        const int wci = __builtin_bit_cast(int, wc);
        float acc0 = 0.0f, acc1 = 0.0f;
        #pragma unroll
        for (int j = 0; j + 1 < P; j += 2) {
            float w0 = __builtin_bit_cast(float, __builtin_amdgcn_readlane(wci, j));
            float w1 = __builtin_bit_cast(float, __builtin_amdgcn_readlane(wci, j + 1));
            acc0 = fmaf(row[j],     w0, acc0);
            acc1 = fmaf(row[j + 1], w1, acc1);
        }
        {
            float w44 = __builtin_bit_cast(float, __builtin_amdgcn_readlane(wci, P - 1));
            acc0 = fmaf(row[P - 1], w44, acc0);
        }
        const float acc = acc0 + acc1;

        // gradient step
        float sgn = (wc > 0.0f) ? 1.0f : ((wc < 0.0f) ? -1.0f : 0.0f);
        float g   = 2.0f * acc - bet + lam_s * sgn + lam_t2 * (wc - wp);
        float wn  = wc - 0.05f * g;
        wn = active ? wn : 0.0f;   // lanes >=P must contribute exact 0 to sums

        // simplex projection: clip, renorm, clip, renorm (uniform rcp, ~1e-7 rel err)
        wn = fminf(fmaxf(wn, 0.0f), 0.15f);
        float s   = wave_sum_bcast(wn);
        wn *= __builtin_amdgcn_rcpf(s + 1e-8f);

        wn = fminf(fmaxf(wn, 0.0f), 0.15f);
        s   = wave_sum_bcast(wn);
        wn *= __builtin_amdgcn_rcpf(s + 1e-8f);

        wc = wn;
    }

    if (active) out[(size_t)b * P + lane] = wc;
}

extern "C" void kernel_launch(void* const* d_in, const int* in_sizes, int n_in,
                              void* d_out, int out_size, void* d_ws, size_t ws_size,
                              hipStream_t stream) {
    const float* sigma  = (const float*)d_in[0];
    const float* beta   = (const float*)d_in[1];
    const float* w_prev = (const float*)d_in[2];
    const float* lls    = (const float*)d_in[3];
    const float* llt    = (const float*)d_in[4];
    float* out = (float*)d_out;

    const int B = in_sizes[1] / P;   // 32768
    drb_kernel<<<B, 64, 0, stream>>>(sigma, beta, w_prev, lls, llt, out);
}